// Round 11
// baseline (105.908 us; speedup 1.0000x reference)
//
#include <hip/hip_runtime.h>
#include <math.h>

#define N_NODES 6144
#define IN_FEAT 512
#define OUTW    512   // NHEADS*OUT_F
#define NH      8
#define ALPHA   0.2f
#define CAP     128   // max neighbors; Binomial(6144,0.01): mean 61, max~96
#define TOTAL_BLKS 2304  // 768 GEMM (bid%3==0) + 1536 CSR, striped for overlap

typedef __attribute__((ext_vector_type(8))) short short8;
typedef __attribute__((ext_vector_type(4))) float f32x4;

__device__ __forceinline__ unsigned short f2bf(float f) {
    unsigned int u = __float_as_uint(f);
    u = (u + 0x7fffu + ((u >> 16) & 1u)) >> 16;   // round-nearest-even
    return (unsigned short)u;
}

// ------- Kernel 0 (striped prep): bid<64 -> W transpose->bf16; else X->bf16 -------
__global__ __launch_bounds__(256) void prep(const float* __restrict__ W,
                                            const float* __restrict__ X,
                                            unsigned short* __restrict__ WT,
                                            unsigned short* __restrict__ XB) {
    const int tid = threadIdx.x;
    if (blockIdx.x < 64) {
        int n  = blockIdx.x * 8 + (tid >> 5);
        int k0 = (tid & 31) * 16;
        union { unsigned short u[16]; uint4 q[2]; } th;
#pragma unroll
        for (int kk = 0; kk < 16; ++kk)
            th.u[kk] = f2bf(W[(size_t)(k0 + kk) * OUTW + n]);
        uint4* ph = (uint4*)(WT + (size_t)n * IN_FEAT + k0);
        ph[0] = th.q[0]; ph[1] = th.q[1];
        return;
    }
    // X convert: 4 rows per block, thread -> 8 consecutive floats
    const size_t base = (size_t)(blockIdx.x - 64) * 2048 + tid * 8;
    float4 f0 = *(const float4*)(X + base);
    float4 f1 = *(const float4*)(X + base + 4);
    union { unsigned short u[8]; uint4 q; } r;
    r.u[0] = f2bf(f0.x); r.u[1] = f2bf(f0.y); r.u[2] = f2bf(f0.z); r.u[3] = f2bf(f0.w);
    r.u[4] = f2bf(f1.x); r.u[5] = f2bf(f1.y); r.u[6] = f2bf(f1.z); r.u[7] = f2bf(f1.w);
    *(uint4*)(XB + base) = r.q;
}

// ------- Kernel 1 (fused, STRIPED roles): bid%3==0 -> MFMA GEMM (+ai/aj);
// else -> CSR compaction. Both resident from t=0: CSR HBM stream overlaps GEMM.
__global__ __launch_bounds__(256) void gemm_csr(const unsigned short* __restrict__ XB,
                                                const unsigned short* __restrict__ BT,
                                                const float* __restrict__ LI,
                                                const float* __restrict__ LJ,
                                                const float* __restrict__ ADJ,
                                                unsigned short* __restrict__ WHB,
                                                float* __restrict__ AI,
                                                float* __restrict__ AJ,
                                                int* __restrict__ NBR,
                                                int* __restrict__ CNT) {
    __shared__ unsigned short As[64][40];
    __shared__ unsigned short Bh[64][40];
    __shared__ float s_ap[64][2], s_jp[64][2];
    const int tid = threadIdx.x;
    const int wave = tid >> 6, lane = tid & 63;
    const int bid = blockIdx.x;
    const int g = bid / 3, r3 = bid - g * 3;

    if (r3 != 0) {
        // ---- CSR compaction: one adjacency row per wave (24*64*4 = 6144 cols) ----
        const int row = (g * 2 + (r3 - 1)) * 4 + wave;
        const f32x4* r4 = (const f32x4*)(ADJ + (size_t)row * N_NODES);
        int* dst = NBR + (size_t)row * CAP;
        const unsigned long long lt = (1ULL << lane) - 1;
        int base = 0;
#pragma unroll
        for (int q = 0; q < 24; ++q) {
            f32x4 v = __builtin_nontemporal_load(r4 + q * 64 + lane);
            int j = (q * 64 + lane) * 4;
#pragma unroll
            for (int c = 0; c < 4; ++c) {
                bool pred = v[c] > 0.5f;
                unsigned long long m = __ballot(pred);
                if (pred) {
                    int p = base + __popcll(m & lt);
                    if (p < CAP) dst[p] = j + c;
                }
                base += __popcll(m);
            }
        }
        if (lane == 0) CNT[row] = min(base, CAP);
        return;
    }

    // ---- GEMM: 64x64 tile; g -> (head, row-tile); bf16 inputs prestaged ----
    const int bn = (g & 7) * 64, bm = (g >> 3) * 64;
    const int head = g & 7;
    const int wm0 = (wave & 1) * 32, wn0 = (wave >> 1) * 32;
    const int lm = lane & 15, lg = lane >> 4;
    const int ar = tid >> 2, akq = (tid & 3) * 8;
    f32x4 acc[2][2] = {};
    for (int k0 = 0; k0 < IN_FEAT; k0 += 32) {
        *(uint4*)&As[ar][akq] = *(const uint4*)(XB + (size_t)(bm + ar) * IN_FEAT + k0 + akq);
        *(uint4*)&Bh[ar][akq] = *(const uint4*)(BT + (size_t)(bn + ar) * IN_FEAT + k0 + akq);
        __syncthreads();
        short8 a0  = *(const short8*)&As[wm0 + lm][lg * 8];
        short8 a1  = *(const short8*)&As[wm0 + 16 + lm][lg * 8];
        short8 bh0 = *(const short8*)&Bh[wn0 + lm][lg * 8];
        short8 bh1 = *(const short8*)&Bh[wn0 + 16 + lm][lg * 8];
        acc[0][0] = __builtin_amdgcn_mfma_f32_16x16x32_bf16(a0, bh0, acc[0][0], 0, 0, 0);
        acc[0][1] = __builtin_amdgcn_mfma_f32_16x16x32_bf16(a0, bh1, acc[0][1], 0, 0, 0);
        acc[1][0] = __builtin_amdgcn_mfma_f32_16x16x32_bf16(a1, bh0, acc[1][0], 0, 0, 0);
        acc[1][1] = __builtin_amdgcn_mfma_f32_16x16x32_bf16(a1, bh1, acc[1][1], 0, 0, 0);
        __syncthreads();
    }
#pragma unroll
    for (int fm = 0; fm < 2; ++fm)
#pragma unroll
        for (int fn = 0; fn < 2; ++fn)
#pragma unroll
            for (int r = 0; r < 4; ++r) {
                int row = bm + wm0 + fm * 16 + lg * 4 + r;
                int col = bn + wn0 + fn * 16 + lm;
                WHB[(size_t)row * OUTW + col] = f2bf(acc[fm][fn][r]);
            }
    float liv0 = LI[bn + wn0 + lm], liv1 = LI[bn + wn0 + 16 + lm];
    float ljv0 = LJ[bn + wn0 + lm], ljv1 = LJ[bn + wn0 + 16 + lm];
#pragma unroll
    for (int fm = 0; fm < 2; ++fm)
#pragma unroll
        for (int r = 0; r < 4; ++r) {
            float pa = acc[fm][0][r] * liv0 + acc[fm][1][r] * liv1;
            float pj = acc[fm][0][r] * ljv0 + acc[fm][1][r] * ljv1;
#pragma unroll
            for (int off = 1; off < 16; off <<= 1) {
                pa += __shfl_xor(pa, off);
                pj += __shfl_xor(pj, off);
            }
            if (lm == 0) {
                int row = wm0 + fm * 16 + lg * 4 + r;
                s_ap[row][wave >> 1] = pa;
                s_jp[row][wave >> 1] = pj;
            }
        }
    __syncthreads();
    if (tid < 64) {
        AI[(size_t)(bm + tid) * NH + head] = s_ap[tid][0] + s_ap[tid][1];
        AJ[(size_t)(bm + tid) * NH + head] = s_jp[tid][0] + s_jp[tid][1];
    }
}

// ---- Kernel 2: softmax + aggregation, head-half split for XCD-L2 residency ----
// block (i, half): heads [half*4, half*4+4); whb col-slab = 3.15MB < 4MB L2.
// Grid x-fastest -> all half-0 blocks run before half-1 (temporal slab split).
// Phase D: 16B/lane, lanes 0-31 -> neighbor k, lanes 32-63 -> k+1 (2 rows/wave-iter).
__global__ __launch_bounds__(256) void gat_attn(const unsigned short* __restrict__ WHB,
                                                const float* __restrict__ AI,
                                                const float* __restrict__ AJ,
                                                const int* __restrict__ NBR,
                                                const int* __restrict__ CNT,
                                                float* __restrict__ OUT) {
    __shared__ int   s_nbr[CAP];
    __shared__ float s_p[CAP][5];
    __shared__ float s_comb[4][2][256];
    __shared__ float s_ai[4];
    __shared__ float s_red[4][4];
    __shared__ float s_m[4];
    __shared__ float s_d[4];

    const int i    = blockIdx.x;
    const int half = blockIdx.y;
    const int tid  = threadIdx.x;
    const int wid  = tid >> 6, lane = tid & 63;
    const int nc   = min(CNT[i], CAP);

    if (tid < 4) s_ai[tid] = AI[i * 8 + half * 4 + tid];
    if (tid < nc) s_nbr[tid] = NBR[(size_t)i * CAP + tid];
    __syncthreads();

    // Phase B: scores for this half's 4 heads (single pass, nc <= 128).
    float mx[4] = {-1e30f, -1e30f, -1e30f, -1e30f};
    if (tid < nc) {
        int j = s_nbr[tid];
        float4 a0 = *(const float4*)(AJ + (size_t)j * 8 + half * 4);
        float z[4] = {a0.x, a0.y, a0.z, a0.w};
#pragma unroll
        for (int h = 0; h < 4; ++h) {
            float zz = s_ai[h] + z[h];
            float s  = zz > 0.f ? zz : ALPHA * zz;
            s_p[tid][h] = s;
            mx[h] = fmaxf(mx[h], s);
        }
    }
#pragma unroll
    for (int off = 32; off > 0; off >>= 1)
#pragma unroll
        for (int h = 0; h < 4; ++h) mx[h] = fmaxf(mx[h], __shfl_down(mx[h], off));
    if (lane == 0)
#pragma unroll
        for (int h = 0; h < 4; ++h) s_red[wid][h] = mx[h];
    __syncthreads();
    if (tid < 4)
        s_m[tid] = fmaxf(fmaxf(s_red[0][tid], s_red[1][tid]),
                         fmaxf(s_red[2][tid], s_red[3][tid]));
    __syncthreads();

    // Phase C: exp + denom.
    float sm[4] = {0.f, 0.f, 0.f, 0.f};
    if (tid < nc) {
#pragma unroll
        for (int h = 0; h < 4; ++h) {
            float p = __expf(s_p[tid][h] - s_m[h]);
            s_p[tid][h] = p;
            sm[h] += p;
        }
    }
#pragma unroll
    for (int off = 32; off > 0; off >>= 1)
#pragma unroll
        for (int h = 0; h < 4; ++h) sm[h] += __shfl_down(sm[h], off);
    if (lane == 0)
#pragma unroll
        for (int h = 0; h < 4; ++h) s_red[wid][h] = sm[h];
    __syncthreads();
    if (tid < 4)
        s_d[tid] = s_red[0][tid] + s_red[1][tid] + s_red[2][tid] + s_red[3][tid];
    __syncthreads();

    // Phase D: lanes 0-31 -> neighbor k, lanes 32-63 -> k+1; 16B/lane; 3-deep prefetch.
    const int sub = lane >> 5;
    const int c32 = lane & 31;          // 8-col group within the half
    const int hd  = c32 >> 3;           // local head 0..3
    const unsigned short* wbase = WHB + (size_t)half * 256 + c32 * 8;
    float a8[8] = {};
    uint4 p0 = {}, p1 = {}, p2 = {};
    int k = wid * 2 + sub;              // k advances by 8 (4 waves x 2 subs)
    if (k < nc)      p0 = *(const uint4*)(wbase + (size_t)s_nbr[k] * OUTW);
    if (k + 8 < nc)  p1 = *(const uint4*)(wbase + (size_t)s_nbr[k + 8] * OUTW);
    if (k + 16 < nc) p2 = *(const uint4*)(wbase + (size_t)s_nbr[k + 16] * OUTW);
    for (; k < nc; k += 8) {
        uint4 cur = p0;
        p0 = p1; p1 = p2;
        if (k + 24 < nc) p2 = *(const uint4*)(wbase + (size_t)s_nbr[k + 24] * OUTW);
        float p = s_p[k][hd];
        unsigned int uu[4] = {cur.x, cur.y, cur.z, cur.w};
#pragma unroll
        for (int q = 0; q < 4; ++q) {
            float lo = __uint_as_float(uu[q] << 16);
            float hi = __uint_as_float(uu[q] & 0xFFFF0000u);
            a8[2 * q]     += p * lo;
            a8[2 * q + 1] += p * hi;
        }
    }
#pragma unroll
    for (int q = 0; q < 8; ++q) s_comb[wid][sub][c32 * 8 + q] = a8[q];
    __syncthreads();
    if (tid < 64) {
        int c0 = tid * 4;
        int hh = tid >> 4;              // local head
        float4 r0 = *(const float4*)&s_comb[0][0][c0];
        float4 r1 = *(const float4*)&s_comb[0][1][c0];
        float4 r2 = *(const float4*)&s_comb[1][0][c0];
        float4 r3 = *(const float4*)&s_comb[1][1][c0];
        float4 r4 = *(const float4*)&s_comb[2][0][c0];
        float4 r5 = *(const float4*)&s_comb[2][1][c0];
        float4 r6 = *(const float4*)&s_comb[3][0][c0];
        float4 r7 = *(const float4*)&s_comb[3][1][c0];
        float inv = 1.0f / s_d[hh];
        f32x4 res;
        res.x = (r0.x + r1.x + r2.x + r3.x + r4.x + r5.x + r6.x + r7.x) * inv;
        res.y = (r0.y + r1.y + r2.y + r3.y + r4.y + r5.y + r6.y + r7.y) * inv;
        res.z = (r0.z + r1.z + r2.z + r3.z + r4.z + r5.z + r6.z + r7.z) * inv;
        res.w = (r0.w + r1.w + r2.w + r3.w + r4.w + r5.w + r6.w + r7.w) * inv;
        // nontemporal: don't evict the whb slab with the OUT write stream
        __builtin_nontemporal_store(res,
            (f32x4*)(OUT + (size_t)i * OUTW + half * 256 + c0));
    }
}

extern "C" void kernel_launch(void* const* d_in, const int* in_sizes, int n_in,
                              void* d_out, int out_size, void* d_ws, size_t ws_size,
                              hipStream_t stream) {
    const float* x   = (const float*)d_in[0];
    const float* adj = (const float*)d_in[1];
    const float* w   = (const float*)d_in[2];
    const float* li  = (const float*)d_in[3];
    const float* lj  = (const float*)d_in[4];
    float* out = (float*)d_out;

    unsigned short* whb = (unsigned short*)d_ws;                 // 6144*512 bf16
    float* ai = (float*)(whb + (size_t)N_NODES * OUTW);          // 6144*8 f32
    float* aj = ai + (size_t)N_NODES * NH;
    unsigned short* wt = (unsigned short*)(aj + (size_t)N_NODES * NH);  // 512*512 bf16
    unsigned short* xb = wt + (size_t)OUTW * IN_FEAT;            // 6144*512 bf16
    int* nbr = (int*)(xb + (size_t)N_NODES * IN_FEAT);           // 6144*128 int
    int* cnt = nbr + (size_t)N_NODES * CAP;                      // 6144 int

    prep<<<64 + N_NODES / 4, 256, 0, stream>>>(w, x, wt, xb);
    gemm_csr<<<TOTAL_BLKS, 256, 0, stream>>>(
        xb, wt, li, lj, adj, whb, ai, aj, nbr, cnt);
    gat_attn<<<dim3(N_NODES, 2), 256, 0, stream>>>(whb, ai, aj, nbr, cnt, out);
}

// Round 12
// 101.304 us; speedup vs baseline: 1.0454x; 1.0454x over previous
//
#include <hip/hip_runtime.h>
#include <math.h>

#define N_NODES 6144
#define IN_FEAT 512
#define OUTW    512   // NHEADS*OUT_F
#define NH      8
#define ALPHA   0.2f
#define CAP     128   // max neighbors; Binomial(6144,0.01): mean 61, max~96
#define TOTAL_BLKS 2304  // 768 GEMM (bid%3==0) + 1536 CSR, striped for overlap

typedef __attribute__((ext_vector_type(8))) short short8;
typedef __attribute__((ext_vector_type(4))) float f32x4;

__device__ __forceinline__ unsigned short f2bf(float f) {
    unsigned int u = __float_as_uint(f);
    u = (u + 0x7fffu + ((u >> 16) & 1u)) >> 16;   // round-nearest-even
    return (unsigned short)u;
}

// ------- Kernel 0: w [K=512][N=512] -> transposed bf16 [n][k] -------
__global__ __launch_bounds__(256) void conv_w(const float* __restrict__ W,
                                              unsigned short* __restrict__ WThi) {
    int n  = blockIdx.x * 8 + (threadIdx.x >> 5);
    int k0 = (threadIdx.x & 31) * 16;
    union { unsigned short u[16]; uint4 q[2]; } th;
#pragma unroll
    for (int kk = 0; kk < 16; ++kk)
        th.u[kk] = f2bf(W[(size_t)(k0 + kk) * OUTW + n]);
    uint4* ph = (uint4*)(WThi + (size_t)n * IN_FEAT + k0);
    ph[0] = th.q[0]; ph[1] = th.q[1];
}

// ------- Kernel 1 (fused, STRIPED roles): bid%3==0 -> MFMA GEMM (+ai/aj);
// else -> CSR compaction. Striping keeps both resident from t=0, so the
// HBM-bound CSR stream overlaps the MFMA/LDS-bound GEMM.
__global__ __launch_bounds__(256) void gemm_csr(const float* __restrict__ X,
                                                const unsigned short* __restrict__ BThi,
                                                const float* __restrict__ LI,
                                                const float* __restrict__ LJ,
                                                const float* __restrict__ ADJ,
                                                unsigned short* __restrict__ WHB,
                                                float* __restrict__ AI,
                                                float* __restrict__ AJ,
                                                int* __restrict__ NBR,
                                                int* __restrict__ CNT) {
    __shared__ unsigned short As[64][40];
    __shared__ unsigned short Bh[64][40];
    __shared__ float s_ap[64][2], s_jp[64][2];
    const int tid = threadIdx.x;
    const int wave = tid >> 6, lane = tid & 63;
    const int bid = blockIdx.x;
    const int g = bid / 3, r3 = bid - g * 3;

    if (r3 != 0) {
        // ---- CSR compaction: one adjacency row per wave (24*64*4 = 6144 cols) ----
        const int row = (g * 2 + (r3 - 1)) * 4 + wave;
        const f32x4* r4 = (const f32x4*)(ADJ + (size_t)row * N_NODES);
        int* dst = NBR + (size_t)row * CAP;
        const unsigned long long lt = (1ULL << lane) - 1;
        int base = 0;
#pragma unroll
        for (int q = 0; q < 24; ++q) {
            f32x4 v = __builtin_nontemporal_load(r4 + q * 64 + lane);
            int j = (q * 64 + lane) * 4;
#pragma unroll
            for (int c = 0; c < 4; ++c) {
                bool pred = v[c] > 0.5f;
                unsigned long long m = __ballot(pred);
                if (pred) {
                    int p = base + __popcll(m & lt);
                    if (p < CAP) dst[p] = j + c;
                }
                base += __popcll(m);
            }
        }
        if (lane == 0) CNT[row] = min(base, CAP);
        return;
    }

    // ---- GEMM: 64x64 tile; g -> (head, row-tile); single-term bf16 ----
    const int bn = (g & 7) * 64, bm = (g >> 3) * 64;
    const int head = g & 7;
    const int wm0 = (wave & 1) * 32, wn0 = (wave >> 1) * 32;
    const int lm = lane & 15, lg = lane >> 4;
    const int ar = tid >> 2, akq = (tid & 3) * 8;
    f32x4 acc[2][2] = {};
    for (int k0 = 0; k0 < IN_FEAT; k0 += 32) {
        const float* ap = X + (size_t)(bm + ar) * IN_FEAT + k0 + akq;
        float4 f0 = *(const float4*)ap;
        float4 f1 = *(const float4*)(ap + 4);
        union { unsigned short u[8]; uint4 q; } ah;
        ah.u[0] = f2bf(f0.x); ah.u[1] = f2bf(f0.y);
        ah.u[2] = f2bf(f0.z); ah.u[3] = f2bf(f0.w);
        ah.u[4] = f2bf(f1.x); ah.u[5] = f2bf(f1.y);
        ah.u[6] = f2bf(f1.z); ah.u[7] = f2bf(f1.w);
        *(uint4*)&As[ar][akq] = ah.q;
        *(uint4*)&Bh[ar][akq] = *(const uint4*)(BThi + (size_t)(bn + ar) * IN_FEAT + k0 + akq);
        __syncthreads();
        short8 a0  = *(const short8*)&As[wm0 + lm][lg * 8];
        short8 a1  = *(const short8*)&As[wm0 + 16 + lm][lg * 8];
        short8 bh0 = *(const short8*)&Bh[wn0 + lm][lg * 8];
        short8 bh1 = *(const short8*)&Bh[wn0 + 16 + lm][lg * 8];
        acc[0][0] = __builtin_amdgcn_mfma_f32_16x16x32_bf16(a0, bh0, acc[0][0], 0, 0, 0);
        acc[0][1] = __builtin_amdgcn_mfma_f32_16x16x32_bf16(a0, bh1, acc[0][1], 0, 0, 0);
        acc[1][0] = __builtin_amdgcn_mfma_f32_16x16x32_bf16(a1, bh0, acc[1][0], 0, 0, 0);
        acc[1][1] = __builtin_amdgcn_mfma_f32_16x16x32_bf16(a1, bh1, acc[1][1], 0, 0, 0);
        __syncthreads();
    }
#pragma unroll
    for (int fm = 0; fm < 2; ++fm)
#pragma unroll
        for (int fn = 0; fn < 2; ++fn)
#pragma unroll
            for (int r = 0; r < 4; ++r) {
                int row = bm + wm0 + fm * 16 + lg * 4 + r;
                int col = bn + wn0 + fn * 16 + lm;
                WHB[(size_t)row * OUTW + col] = f2bf(acc[fm][fn][r]);
            }
    float liv0 = LI[bn + wn0 + lm], liv1 = LI[bn + wn0 + 16 + lm];
    float ljv0 = LJ[bn + wn0 + lm], ljv1 = LJ[bn + wn0 + 16 + lm];
#pragma unroll
    for (int fm = 0; fm < 2; ++fm)
#pragma unroll
        for (int r = 0; r < 4; ++r) {
            float pa = acc[fm][0][r] * liv0 + acc[fm][1][r] * liv1;
            float pj = acc[fm][0][r] * ljv0 + acc[fm][1][r] * ljv1;
#pragma unroll
            for (int off = 1; off < 16; off <<= 1) {
                pa += __shfl_xor(pa, off);
                pj += __shfl_xor(pj, off);
            }
            if (lm == 0) {
                int row = wm0 + fm * 16 + lg * 4 + r;
                s_ap[row][wave >> 1] = pa;
                s_jp[row][wave >> 1] = pj;
            }
        }
    __syncthreads();
    if (tid < 64) {
        AI[(size_t)(bm + tid) * NH + head] = s_ap[tid][0] + s_ap[tid][1];
        AJ[(size_t)(bm + tid) * NH + head] = s_jp[tid][0] + s_jp[tid][1];
    }
}

// ---- Kernel 2: softmax + aggregation from CSR (no adjacency scan) ----
// Phase D gather: depth-6 ring of UNCONDITIONAL clamped loads so the compiler
// keeps 6 x 16B per lane in flight (conditional prefetch can't be hoisted).
__global__ __launch_bounds__(256) void gat_attn(const unsigned short* __restrict__ WHB,
                                                const float* __restrict__ AI,
                                                const float* __restrict__ AJ,
                                                const int* __restrict__ NBR,
                                                const int* __restrict__ CNT,
                                                float* __restrict__ OUT) {
    __shared__ int   s_nbr[CAP];
    __shared__ float s_p[CAP][9];
    __shared__ float s_comb[4][512];
    __shared__ float s_ai[8];
    __shared__ float s_red[4][8];
    __shared__ float s_m[8];
    __shared__ float s_d[8];

    const int i   = blockIdx.x;
    const int tid = threadIdx.x;
    const int wid = tid >> 6, lane = tid & 63;
    const int nc  = min(CNT[i], CAP);

    if (tid < 8) s_ai[tid] = AI[i * 8 + tid];
    if (tid < nc) s_nbr[tid] = NBR[(size_t)i * CAP + tid];
    __syncthreads();

    // Phase B: scores (single pass, nc <= 128 < 256) + per-head max.
    float mx[8];
#pragma unroll
    for (int h = 0; h < 8; ++h) mx[h] = -1e30f;
    if (tid < nc) {
        int j = s_nbr[tid];
        const float* ajp = AJ + (size_t)j * 8;
        float4 a0 = *(const float4*)ajp;
        float4 a1 = *(const float4*)(ajp + 4);
        float z[8] = {a0.x, a0.y, a0.z, a0.w, a1.x, a1.y, a1.z, a1.w};
#pragma unroll
        for (int h = 0; h < 8; ++h) {
            float zz = s_ai[h] + z[h];
            float s  = zz > 0.f ? zz : ALPHA * zz;
            s_p[tid][h] = s;
            mx[h] = fmaxf(mx[h], s);
        }
    }
#pragma unroll
    for (int off = 32; off > 0; off >>= 1)
#pragma unroll
        for (int h = 0; h < 8; ++h) mx[h] = fmaxf(mx[h], __shfl_down(mx[h], off));
    if (lane == 0)
#pragma unroll
        for (int h = 0; h < 8; ++h) s_red[wid][h] = mx[h];
    __syncthreads();
    if (tid < 8)
        s_m[tid] = fmaxf(fmaxf(s_red[0][tid], s_red[1][tid]),
                         fmaxf(s_red[2][tid], s_red[3][tid]));
    __syncthreads();

    // Phase C: exp + denom.
    float sm[8] = {0.f, 0.f, 0.f, 0.f, 0.f, 0.f, 0.f, 0.f};
    if (tid < nc) {
#pragma unroll
        for (int h = 0; h < 8; ++h) {
            float p = __expf(s_p[tid][h] - s_m[h]);
            s_p[tid][h] = p;
            sm[h] += p;
        }
    }
#pragma unroll
    for (int off = 32; off > 0; off >>= 1)
#pragma unroll
        for (int h = 0; h < 8; ++h) sm[h] += __shfl_down(sm[h], off);
    if (lane == 0)
#pragma unroll
        for (int h = 0; h < 8; ++h) s_red[wid][h] = sm[h];
    __syncthreads();
    if (tid < 8)
        s_d[tid] = s_red[0][tid] + s_red[1][tid] + s_red[2][tid] + s_red[3][tid];
    __syncthreads();

    // Phase D: wave w takes k ≡ w (mod 4); full 1024B row per wave-iter
    // (lane l owns cols 8l..8l+7); depth-6 unconditional ring.
    const int hd = lane >> 3;
    float a8[8] = {};
    const int last = nc - 1;          // nc >= 1 (self-loop)
    const unsigned short* wb = WHB + lane * 8;
#define LDROW(kk) (*(const uint4*)(wb + (size_t)s_nbr[(kk) <= last ? (kk) : last] * OUTW))
    int k = wid;
    if (k <= last) {
        uint4 f0 = LDROW(k),      f1 = LDROW(k + 4),  f2 = LDROW(k + 8);
        uint4 f3 = LDROW(k + 12), f4 = LDROW(k + 16), f5 = LDROW(k + 20);
        for (; k <= last; k += 4) {
            uint4 cur = f0;
            f0 = f1; f1 = f2; f2 = f3; f3 = f4; f4 = f5;
            f5 = LDROW(k + 24);
            float p = s_p[k][hd];
            unsigned int uu[4] = {cur.x, cur.y, cur.z, cur.w};
#pragma unroll
            for (int q = 0; q < 4; ++q) {
                float lo = __uint_as_float(uu[q] << 16);
                float hi = __uint_as_float(uu[q] & 0xFFFF0000u);
                a8[2 * q]     += p * lo;
                a8[2 * q + 1] += p * hi;
            }
        }
    }
#undef LDROW
#pragma unroll
    for (int q = 0; q < 8; ++q) s_comb[wid][lane * 8 + q] = a8[q];
    __syncthreads();
    if (tid < 128) {
        int c0 = tid * 4;
        int hh = tid >> 4;
        float4 v0 = *(const float4*)&s_comb[0][c0];
        float4 v1 = *(const float4*)&s_comb[1][c0];
        float4 v2 = *(const float4*)&s_comb[2][c0];
        float4 v3 = *(const float4*)&s_comb[3][c0];
        float inv = 1.0f / s_d[hh];
        f32x4 res;
        res.x = (v0.x + v1.x + v2.x + v3.x) * inv;
        res.y = (v0.y + v1.y + v2.y + v3.y) * inv;
        res.z = (v0.z + v1.z + v2.z + v3.z) * inv;
        res.w = (v0.w + v1.w + v2.w + v3.w) * inv;
        // nontemporal: don't evict whb with the OUT write stream
        __builtin_nontemporal_store(res, (f32x4*)(OUT + (size_t)i * OUTW + c0));
    }
}

extern "C" void kernel_launch(void* const* d_in, const int* in_sizes, int n_in,
                              void* d_out, int out_size, void* d_ws, size_t ws_size,
                              hipStream_t stream) {
    const float* x   = (const float*)d_in[0];
    const float* adj = (const float*)d_in[1];
    const float* w   = (const float*)d_in[2];
    const float* li  = (const float*)d_in[3];
    const float* lj  = (const float*)d_in[4];
    float* out = (float*)d_out;

    unsigned short* whb = (unsigned short*)d_ws;                 // 6144*512 bf16
    float* ai = (float*)(whb + (size_t)N_NODES * OUTW);          // 6144*8 f32
    float* aj = ai + (size_t)N_NODES * NH;
    unsigned short* wthi = (unsigned short*)(aj + (size_t)N_NODES * NH);
    int* nbr = (int*)(wthi + (size_t)OUTW * IN_FEAT);            // 6144*128 int
    int* cnt = nbr + (size_t)N_NODES * CAP;                      // 6144 int

    conv_w<<<OUTW / 8, 256, 0, stream>>>(w, wthi);
    gemm_csr<<<TOTAL_BLKS, 256, 0, stream>>>(
        x, wthi, li, lj, adj, whb, ai, aj, nbr, cnt);
    gat_attn<<<N_NODES, 256, 0, stream>>>(whb, ai, aj, nbr, cnt, out);
}